// Round 9
// baseline (952.758 us; speedup 1.0000x reference)
//
#include <hip/hip_runtime.h>
#include <hip/hip_fp16.h>
#include <cmath>

#define NN 50000
#define NE 1600000
#define NG 64
#define CAP 96    // slots per row; deg ~ Poisson(32), P(deg>=96) ~ e^-41 -> safe
#define NPART 8   // row partitions ~ XCDs; slot region/partition = 2.4 MB < 4 MiB L2
#define PROWS 6250

typedef __attribute__((ext_vector_type(8))) short short8_t;
typedef __attribute__((ext_vector_type(4))) float floatx4;
typedef __attribute__((ext_vector_type(4))) unsigned short us4;
typedef __attribute__((ext_vector_type(8))) unsigned short us8;

static __device__ __forceinline__ float softplusf(float x) {
    return fmaxf(x, 0.0f) + log1pf(expf(-fabsf(x)));
}

static __device__ __forceinline__ float bf2f(unsigned short u) {
    return __uint_as_float(((unsigned)u) << 16);
}
static __device__ __forceinline__ unsigned short f2bf(float x) {
    unsigned u = __float_as_uint(x);
    unsigned t = (u >> 16) & 1u;
    return (unsigned short)((u + 0x7FFFu + t) >> 16);  // RNE
}
static __device__ __forceinline__ float h2f(unsigned u) {
    __half_raw r; r.x = (unsigned short)(u & 0xFFFFu);
    return __half2float(__half(r));
}
static __device__ __forceinline__ unsigned short f2h(float x) {
    __half h = __float2half_rn(x);
    return static_cast<__half_raw>(h).x;
}

// exact split x = hi + lo (bf16 each, ~2^-16 relative residual)
static __device__ __forceinline__ void split_bf16(float x, unsigned short& hi, unsigned short& lo) {
    unsigned u = __float_as_uint(x);
    unsigned hb = u & 0xFFFF0000u;
    hi = (unsigned short)(hb >> 16);
    float r = x - __uint_as_float(hb);   // exact
    lo = f2bf(r);
}

// XCD-partitioned slotted build + fused deg accumulation. Blocks with
// (blockIdx&7)==p handle rows [p*PROWS,(p+1)*PROWS); slot region (2.4 MB),
// cnt and deg (25 KB each) per partition stay in that XCD's L2.
__global__ __launch_bounds__(256) void k_slot2(const int* __restrict__ row,
                                               const int* __restrict__ col,
                                               const float* __restrict__ w,
                                               int* __restrict__ cnt,
                                               float* __restrict__ deg,
                                               unsigned* __restrict__ pslots) {
    const int part = blockIdx.x & (NPART - 1);
    const int bid = blockIdx.x >> 3;
    const int nb = gridDim.x >> 3;
    const int rlo = part * PROWS;
    const int rhi = rlo + PROWS;
    for (int e = bid * 256 + threadIdx.x; e < NE; e += nb * 256) {
        int r = row[e];
        if (r >= rlo && r < rhi) {
            float wv = w[e];
            int k = atomicAdd(&cnt[r], 1);
            atomicAdd(&deg[r], wv);
            k = min(k, CAP - 1);  // defensive
            pslots[(size_t)r * CAP + k] = ((unsigned)col[e] << 16) | (unsigned)f2h(wv);
        }
    }
}

__global__ void k_dinv(float* __restrict__ deg) {
    int i = blockIdx.x * blockDim.x + threadIdx.x;
    if (i < NN) {
        float d = deg[i];
        deg[i] = (d > 0.0f) ? rsqrtf(d) : 0.0f;
    }
}

// In-place: weight half of pslot <- fp16(-w * dinv[r] * dinv[col])
__global__ __launch_bounds__(256) void k_repack(const int* __restrict__ cnt,
                                                unsigned* __restrict__ pslots,
                                                const float* __restrict__ dinv) {
    int tid = threadIdx.x;
    int lane = tid & 15;
    int node = blockIdx.x * 16 + (tid >> 4);
    if (node >= NN) return;
    int e = cnt[node];
    float dr = dinv[node];
    unsigned* pb = pslots + (size_t)node * CAP;
    for (int k = lane; k < e; k += 16) {
        unsigned s = pb[k];
        float wv = -h2f(s) * dr * dinv[s >> 16];
        pb[k] = (s & 0xFFFF0000u) | (unsigned)f2h(wv);
    }
}

// Wcat1 (128 x 48) = [W0-W2 | W1 | W2] from W1 input (3,128,16)
__global__ void k_wcat1(const float* __restrict__ W1, float* __restrict__ wc) {
    int i = blockIdx.x * blockDim.x + threadIdx.x;
    if (i < 128 * 48) {
        int k = i / 48, j = i - k * 48;
        float v;
        if (j < 16)      v = W1[k * 16 + j] - W1[2 * 2048 + k * 16 + j];
        else if (j < 32) v = W1[2048 + k * 16 + (j - 16)];
        else             v = W1[2 * 2048 + k * 16 + (j - 32)];
        wc[i] = v;
    }
}

// Split W (K,N) fp32 into transposed hi/lo bf16: hiT/loT are (N,K)
__global__ void k_wsplit(const float* __restrict__ W, int K, int N,
                         unsigned short* __restrict__ hiT, unsigned short* __restrict__ loT) {
    int idx = blockIdx.x * 256 + threadIdx.x;
    if (idx < K * N) {
        int k = idx / N, n = idx - k * N;
        unsigned short h, l;
        split_bf16(W[idx], h, l);
        hiT[(size_t)n * K + k] = h;
        loT[(size_t)n * K + k] = l;
    }
}

#define ASTR 40  // padded LDS row stride in ushorts (32 + 8)

// ---------------- MFMA GEMM, fp32 A (3-term split), bf16 C. Layer 1 only.
__global__ __launch_bounds__(256, 2) void k_gemm_mfma_f32A(
    const float* __restrict__ A, int lda,
    const unsigned short* __restrict__ BhiT,
    const unsigned short* __restrict__ BloT,
    unsigned short* __restrict__ C, int ldc,
    int M, int K, int Ncol)
{
    __shared__ unsigned short Ah[128 * ASTR];
    __shared__ unsigned short Al[128 * ASTR];
    __shared__ unsigned short Bh[128 * ASTR];
    __shared__ unsigned short Bl[128 * ASTR];

    const int tid = threadIdx.x;
    const int lane = tid & 63;
    const int wave = tid >> 6;
    const int wm = wave >> 1, wn = wave & 1;
    const int quad = lane >> 4, l16 = lane & 15;
    const int bm = blockIdx.y * 128, bn = blockIdx.x * 128;
    const int srow = tid >> 1;
    const int skq  = (tid & 1) * 16;

    floatx4 acc[4][4];
#pragma unroll
    for (int i = 0; i < 4; ++i)
#pragma unroll
        for (int j = 0; j < 4; ++j) acc[i][j] = (floatx4){0.f, 0.f, 0.f, 0.f};

    for (int k0 = 0; k0 < K; k0 += 32) {
        float4 a0 = make_float4(0, 0, 0, 0), a1 = a0, a2 = a0, a3 = a0;
        const int ga = bm + srow;
        if (ga < M) {
            const float* Ap = A + (size_t)ga * lda + k0 + skq;
            a0 = *(const float4*)(Ap + 0);
            a1 = *(const float4*)(Ap + 4);
            a2 = *(const float4*)(Ap + 8);
            a3 = *(const float4*)(Ap + 12);
        }
        uint4 bh0 = make_uint4(0, 0, 0, 0), bh1 = bh0, bl0 = bh0, bl1 = bh0;
        const int gb = bn + srow;
        if (gb < Ncol) {
            const unsigned short* ph = BhiT + (size_t)gb * K + k0 + skq;
            const unsigned short* pl = BloT + (size_t)gb * K + k0 + skq;
            bh0 = *(const uint4*)(ph);
            bh1 = *(const uint4*)(ph + 8);
            bl0 = *(const uint4*)(pl);
            bl1 = *(const uint4*)(pl + 8);
        }
        __attribute__((aligned(16))) unsigned short ah[16], al[16];
        const float av[16] = {a0.x, a0.y, a0.z, a0.w, a1.x, a1.y, a1.z, a1.w,
                              a2.x, a2.y, a2.z, a2.w, a3.x, a3.y, a3.z, a3.w};
#pragma unroll
        for (int i = 0; i < 16; ++i) split_bf16(av[i], ah[i], al[i]);

        __syncthreads();
        *(uint4*)&Ah[srow * ASTR + skq]     = *(const uint4*)&ah[0];
        *(uint4*)&Ah[srow * ASTR + skq + 8] = *(const uint4*)&ah[8];
        *(uint4*)&Al[srow * ASTR + skq]     = *(const uint4*)&al[0];
        *(uint4*)&Al[srow * ASTR + skq + 8] = *(const uint4*)&al[8];
        *(uint4*)&Bh[srow * ASTR + skq]     = bh0;
        *(uint4*)&Bh[srow * ASTR + skq + 8] = bh1;
        *(uint4*)&Bl[srow * ASTR + skq]     = bl0;
        *(uint4*)&Bl[srow * ASTR + skq + 8] = bl1;
        __syncthreads();

        short8_t afh[4], afl[4], bfh[4], bfl[4];
#pragma unroll
        for (int t = 0; t < 4; ++t) {
            const int m = wm * 64 + t * 16 + l16;
            afh[t] = *(const short8_t*)&Ah[m * ASTR + quad * 8];
            afl[t] = *(const short8_t*)&Al[m * ASTR + quad * 8];
            const int n = wn * 64 + t * 16 + l16;
            bfh[t] = *(const short8_t*)&Bh[n * ASTR + quad * 8];
            bfl[t] = *(const short8_t*)&Bl[n * ASTR + quad * 8];
        }
#pragma unroll
        for (int i = 0; i < 4; ++i)
#pragma unroll
            for (int j = 0; j < 4; ++j) {
                acc[i][j] = __builtin_amdgcn_mfma_f32_16x16x32_bf16(afh[i], bfh[j], acc[i][j], 0, 0, 0);
                acc[i][j] = __builtin_amdgcn_mfma_f32_16x16x32_bf16(afh[i], bfl[j], acc[i][j], 0, 0, 0);
                acc[i][j] = __builtin_amdgcn_mfma_f32_16x16x32_bf16(afl[i], bfh[j], acc[i][j], 0, 0, 0);
            }
    }

#pragma unroll
    for (int j = 0; j < 4; ++j) {
        const int col = bn + wn * 64 + j * 16 + l16;
        if (col >= Ncol) continue;
#pragma unroll
        for (int i = 0; i < 4; ++i) {
#pragma unroll
            for (int r = 0; r < 4; ++r) {
                const int row = bm + wm * 64 + i * 16 + quad * 4 + r;
                if (row >= M) continue;
                C[(size_t)row * ldc + col] = f2bf(acc[i][j][r]);
            }
        }
    }
}

// ---------------- MFMA GEMM, bf16 A direct (2-term W split). Layers 3/4/5.
__global__ __launch_bounds__(256, 2) void k_gemm_mfma_bf(
    const unsigned short* __restrict__ A, int lda,
    const unsigned short* __restrict__ BhiT,
    const unsigned short* __restrict__ BloT,
    unsigned short* __restrict__ C, int ldc,
    int M, int K, int Ncol,
    const float* __restrict__ bias, int act)
{
    __shared__ unsigned short Ah[128 * ASTR];
    __shared__ unsigned short Bh[128 * ASTR];
    __shared__ unsigned short Bl[128 * ASTR];

    const int tid = threadIdx.x;
    const int lane = tid & 63;
    const int wave = tid >> 6;
    const int wm = wave >> 1, wn = wave & 1;
    const int quad = lane >> 4, l16 = lane & 15;
    const int bm = blockIdx.y * 128, bn = blockIdx.x * 128;
    const int srow = tid >> 1;
    const int skq  = (tid & 1) * 16;

    floatx4 acc[4][4];
#pragma unroll
    for (int i = 0; i < 4; ++i)
#pragma unroll
        for (int j = 0; j < 4; ++j) acc[i][j] = (floatx4){0.f, 0.f, 0.f, 0.f};

    for (int k0 = 0; k0 < K; k0 += 32) {
        uint4 a0 = make_uint4(0, 0, 0, 0), a1 = a0;
        const int ga = bm + srow;
        if (ga < M) {
            const unsigned short* Ap = A + (size_t)ga * lda + k0 + skq;
            a0 = *(const uint4*)(Ap);
            a1 = *(const uint4*)(Ap + 8);
        }
        uint4 bh0 = make_uint4(0, 0, 0, 0), bh1 = bh0, bl0 = bh0, bl1 = bh0;
        const int gb = bn + srow;
        if (gb < Ncol) {
            const unsigned short* ph = BhiT + (size_t)gb * K + k0 + skq;
            const unsigned short* pl = BloT + (size_t)gb * K + k0 + skq;
            bh0 = *(const uint4*)(ph);
            bh1 = *(const uint4*)(ph + 8);
            bl0 = *(const uint4*)(pl);
            bl1 = *(const uint4*)(pl + 8);
        }
        __syncthreads();
        *(uint4*)&Ah[srow * ASTR + skq]     = a0;
        *(uint4*)&Ah[srow * ASTR + skq + 8] = a1;
        *(uint4*)&Bh[srow * ASTR + skq]     = bh0;
        *(uint4*)&Bh[srow * ASTR + skq + 8] = bh1;
        *(uint4*)&Bl[srow * ASTR + skq]     = bl0;
        *(uint4*)&Bl[srow * ASTR + skq + 8] = bl1;
        __syncthreads();

        short8_t afh[4], bfh[4], bfl[4];
#pragma unroll
        for (int t = 0; t < 4; ++t) {
            const int m = wm * 64 + t * 16 + l16;
            afh[t] = *(const short8_t*)&Ah[m * ASTR + quad * 8];
            const int n = wn * 64 + t * 16 + l16;
            bfh[t] = *(const short8_t*)&Bh[n * ASTR + quad * 8];
            bfl[t] = *(const short8_t*)&Bl[n * ASTR + quad * 8];
        }
#pragma unroll
        for (int i = 0; i < 4; ++i)
#pragma unroll
            for (int j = 0; j < 4; ++j) {
                acc[i][j] = __builtin_amdgcn_mfma_f32_16x16x32_bf16(afh[i], bfh[j], acc[i][j], 0, 0, 0);
                acc[i][j] = __builtin_amdgcn_mfma_f32_16x16x32_bf16(afh[i], bfl[j], acc[i][j], 0, 0, 0);
            }
    }

#pragma unroll
    for (int j = 0; j < 4; ++j) {
        const int col = bn + wn * 64 + j * 16 + l16;
        if (col >= Ncol) continue;
        const float bv = bias ? bias[col] : 0.0f;
#pragma unroll
        for (int i = 0; i < 4; ++i) {
#pragma unroll
            for (int r = 0; r < 4; ++r) {
                const int row = bm + wm * 64 + i * 16 + quad * 4 + r;
                if (row >= M) continue;
                float v = acc[i][j][r] + bv;
                if (act) v = softplusf(v);
                C[(size_t)row * ldc + col] = f2bf(v);
            }
        }
    }
}

// fp32-weight vector GEMM with bf16 A and bf16 C (layer 2 only, K=48)
__global__ __launch_bounds__(256) void k_gemm(
    const unsigned short* __restrict__ A, int lda,
    const float* __restrict__ B, int ldb,
    unsigned short* __restrict__ C, int ldc,
    int M, int K, int Ncol,
    const float* __restrict__ bias, int act)
{
    __shared__ float As[16][128];
    __shared__ float Bs[16][128];
    const int tid = threadIdx.x;
    const int tx = tid & 15;
    const int ty = tid >> 4;
    const int bm = blockIdx.y * 128;
    const int bn = blockIdx.x * 128;
    const int arow = tid >> 1;
    const int akq = (tid & 1) * 8;
    const int bkr = tid >> 4;
    const int bcq = (tid & 15) * 8;

    float acc[8][8];
#pragma unroll
    for (int i = 0; i < 8; ++i)
#pragma unroll
        for (int j = 0; j < 8; ++j) acc[i][j] = 0.0f;

    for (int k0 = 0; k0 < K; k0 += 16) {
        uint4 ald = make_uint4(0, 0, 0, 0);
        int gr = bm + arow;
        if (gr < M) ald = *(const uint4*)(A + (size_t)gr * lda + k0 + akq);
        float4 b0 = make_float4(0, 0, 0, 0), b1 = make_float4(0, 0, 0, 0);
        int cb = bn + bcq;
        const float* Bp = B + (k0 + bkr) * ldb;
        if (cb < Ncol)     b0 = *(const float4*)(Bp + cb);
        if (cb + 4 < Ncol) b1 = *(const float4*)(Bp + cb + 4);
        __syncthreads();
        const unsigned short* au = (const unsigned short*)&ald;
#pragma unroll
        for (int i = 0; i < 8; ++i) As[akq + i][arow] = bf2f(au[i]);
        *(float4*)&Bs[bkr][bcq] = b0;
        *(float4*)&Bs[bkr][bcq + 4] = b1;
        __syncthreads();
#pragma unroll
        for (int kk = 0; kk < 16; ++kk) {
            float a[8], b[8];
            float4 t;
            t = *(const float4*)&As[kk][ty * 4];      a[0] = t.x; a[1] = t.y; a[2] = t.z; a[3] = t.w;
            t = *(const float4*)&As[kk][64 + ty * 4]; a[4] = t.x; a[5] = t.y; a[6] = t.z; a[7] = t.w;
            t = *(const float4*)&Bs[kk][tx * 4];      b[0] = t.x; b[1] = t.y; b[2] = t.z; b[3] = t.w;
            t = *(const float4*)&Bs[kk][64 + tx * 4]; b[4] = t.x; b[5] = t.y; b[6] = t.z; b[7] = t.w;
#pragma unroll
            for (int i = 0; i < 8; ++i)
#pragma unroll
                for (int j = 0; j < 8; ++j)
                    acc[i][j] = fmaf(a[i], b[j], acc[i][j]);
        }
    }
#pragma unroll
    for (int i = 0; i < 8; ++i) {
        int r = bm + ((i < 4) ? (ty * 4 + i) : (64 + ty * 4 + i - 4));
        if (r >= M) continue;
#pragma unroll
        for (int j = 0; j < 8; ++j) {
            int cl = bn + ((j < 4) ? (tx * 4 + j) : (64 + tx * 4 + j - 4));
            if (cl >= Ncol) continue;
            float v = acc[i][j];
            if (bias) v += bias[cl];
            if (act) v = softplusf(v);
            C[(size_t)r * ldc + cl] = f2bf(v);
        }
    }
}

// Slotted propagation, packed 4B slots, 4 bf16 feats (8B) per lane, x16 unroll
// (deg ~ 32 -> ~2 main iterations; 16 gathers in flight per lane).
// Slot stream is read non-temporally to preserve L2 for z rows.
__global__ __launch_bounds__(256) void k_prop(
    const int* __restrict__ cnt, const unsigned* __restrict__ pslots,
    const unsigned short* __restrict__ z, int zld, int zoff,
    unsigned short* __restrict__ out, int outld, int ooff,
    int ltw, float alpha,
    const unsigned short* __restrict__ add1, int a1ld, int a1off, float c1,
    const unsigned short* __restrict__ add2, int a2ld, int a2off,
    const float* __restrict__ bias, int act)
{
    const int T = 1 << ltw;
    const int lane = threadIdx.x & (T - 1);
    const int node = blockIdx.x * (256 >> ltw) + (threadIdx.x >> ltw);
    if (node >= NN) return;
    const int f4 = lane * 4;
    const int e = cnt[node];
    const unsigned* base = pslots + (size_t)node * CAP;
    float accA[4] = {0, 0, 0, 0};
    float accB[4] = {0, 0, 0, 0};
    const unsigned short* zp = z + zoff + f4;
    int p = 0;
    for (; p + 16 <= e; p += 16) {
        unsigned s[16];
#pragma unroll
        for (int i = 0; i < 16; ++i) s[i] = __builtin_nontemporal_load(base + p + i);
        us4 zv[16];
#pragma unroll
        for (int i = 0; i < 16; ++i) zv[i] = *(const us4*)(zp + (size_t)(s[i] >> 16) * zld);
#pragma unroll
        for (int i = 0; i < 16; ++i) {
            float wv = h2f(s[i]);
            float* acc = (i & 1) ? accB : accA;
#pragma unroll
            for (int j = 0; j < 4; ++j) acc[j] = fmaf(wv, bf2f(zv[i][j]), acc[j]);
        }
    }
    for (; p + 4 <= e; p += 4) {
        unsigned s0 = __builtin_nontemporal_load(base + p + 0);
        unsigned s1 = __builtin_nontemporal_load(base + p + 1);
        unsigned s2 = __builtin_nontemporal_load(base + p + 2);
        unsigned s3 = __builtin_nontemporal_load(base + p + 3);
        const us4 z0 = *(const us4*)(zp + (size_t)(s0 >> 16) * zld);
        const us4 z1 = *(const us4*)(zp + (size_t)(s1 >> 16) * zld);
        const us4 z2 = *(const us4*)(zp + (size_t)(s2 >> 16) * zld);
        const us4 z3 = *(const us4*)(zp + (size_t)(s3 >> 16) * zld);
        float w0 = h2f(s0), w1 = h2f(s1), w2 = h2f(s2), w3 = h2f(s3);
#pragma unroll
        for (int i = 0; i < 4; ++i) {
            accA[i] = fmaf(w0, bf2f(z0[i]), accA[i]);
            accB[i] = fmaf(w1, bf2f(z1[i]), accB[i]);
            accA[i] = fmaf(w2, bf2f(z2[i]), accA[i]);
            accB[i] = fmaf(w3, bf2f(z3[i]), accB[i]);
        }
    }
    for (; p < e; ++p) {
        unsigned s = __builtin_nontemporal_load(base + p);
        float wv = h2f(s);
        const us4 zv = *(const us4*)(zp + (size_t)(s >> 16) * zld);
#pragma unroll
        for (int i = 0; i < 4; ++i) accA[i] = fmaf(wv, bf2f(zv[i]), accA[i]);
    }
#pragma unroll
    for (int i = 0; i < 4; ++i) accA[i] = alpha * (accA[i] + accB[i]);
    if (add1) {
        const us4 t = *(const us4*)(add1 + (size_t)node * a1ld + a1off + f4);
#pragma unroll
        for (int i = 0; i < 4; ++i) accA[i] = fmaf(c1, bf2f(t[i]), accA[i]);
    }
    if (add2) {
        const us4 t = *(const us4*)(add2 + (size_t)node * a2ld + a2off + f4);
#pragma unroll
        for (int i = 0; i < 4; ++i) accA[i] += bf2f(t[i]);
    }
    if (bias) {
        const float4 t = *(const float4*)(bias + f4);
        accA[0] += t.x; accA[1] += t.y; accA[2] += t.z; accA[3] += t.w;
    }
    if (act) {
#pragma unroll
        for (int i = 0; i < 4; ++i) accA[i] = softplusf(accA[i]);
    }
    us4 o;
#pragma unroll
    for (int i = 0; i < 4; ++i) o[i] = f2bf(accA[i]);
    *(us4*)(out + (size_t)node * outld + ooff + f4) = o;
}

__global__ __launch_bounds__(256) void k_bnstats(const unsigned short* __restrict__ h, int ld, int lc,
                                                 float* __restrict__ stats) {
    const int C = 1 << lc;
    const int tid = threadIdx.x;
    const int c = tid & (C - 1);
    const int rpb = 256 >> lc;
    int r = blockIdx.x * rpb + (tid >> lc);
    const int stride = gridDim.x * rpb;
    float s = 0.0f, q = 0.0f;
    for (; r < NN; r += stride) {
        float v = bf2f(h[(size_t)r * ld + c]);
        s += v;
        q = fmaf(v, v, q);
    }
    __shared__ float shs[256], shq[256];
    shs[tid] = s; shq[tid] = q;
    __syncthreads();
    for (int o = 128; o >= C; o >>= 1) {
        if (tid < o) { shs[tid] += shs[tid + o]; shq[tid] += shq[tid + o]; }
        __syncthreads();
    }
    if (tid < C) {
        atomicAdd(&stats[c], shs[tid]);
        atomicAdd(&stats[128 + c], shq[tid]);
    }
}

// Vectorized BN apply: 8 elems/thread.
__global__ void k_bnapply(unsigned short* __restrict__ h, int ld, int lc,
                          const float* __restrict__ stats,
                          const float* __restrict__ g, const float* __restrict__ be) {
    int idx = blockIdx.x * 256 + threadIdx.x;        // in units of 8 elems
    const int C8 = 1 << (lc - 3);
    if (idx >= NN * C8) return;
    int r = idx >> (lc - 3);
    int c0 = (idx & (C8 - 1)) << 3;
    const float invN = 1.0f / (float)NN;
    unsigned short* hp = h + (size_t)r * ld + c0;
    us8 v = *(const us8*)hp;
    us8 o;
#pragma unroll
    for (int i = 0; i < 8; ++i) {
        int c = c0 + i;
        float m = stats[c] * invN;
        float var = fmaf(stats[128 + c], invN, -m * m);
        var = fmaxf(var, 0.0f);
        float inv = rsqrtf(var + 1e-5f);
        o[i] = f2bf(fmaf(g[c] * inv, bf2f(v[i]) - m, be[c]));
    }
    *(us8*)hp = o;
}

static __device__ __forceinline__ int lower_bound_dev(const int* __restrict__ b, int val) {
    int lo = 0, hi = NN;
    while (lo < hi) {
        int mid = (lo + hi) >> 1;
        if (b[mid] < val) lo = mid + 1; else hi = mid;
    }
    return lo;
}

__global__ void k_gbounds(const int* __restrict__ batch, int* __restrict__ gb) {
    int g = threadIdx.x;
    if (g <= NG) gb[g] = (g == NG) ? NN : lower_bound_dev(batch, g);
}

// Pool stage 1 over bf16 h5.
__global__ __launch_bounds__(256) void k_pool1(const unsigned short* __restrict__ h,
                                               const int* __restrict__ gb,
                                               float* __restrict__ partial) {
    int g = blockIdx.y;
    int j = blockIdx.x;
    int start = gb[g], end = gb[g + 1];
    int len = end - start;
    int chunk = (len + 15) >> 4;
    int s = start + j * chunk;
    int e = min(s + chunk, end);
    int c = threadIdx.x;
    float mx = -INFINITY, sum = 0.0f;
    for (int r = s; r < e; ++r) {
        float v = bf2f(h[(size_t)r * 256 + c]);
        mx = fmaxf(mx, v);
        sum += v;
    }
    size_t base = ((size_t)(g * 16 + j)) * 512;
    partial[base + c] = mx;
    partial[base + 256 + c] = sum;
}

// Fused pool stage 2 + dense + log_softmax: 64 blocks.
__global__ __launch_bounds__(256) void k_pool2d(const float* __restrict__ partial,
                                                const int* __restrict__ gb,
                                                const float* __restrict__ Wd,
                                                const float* __restrict__ bd,
                                                float* __restrict__ out) {
    __shared__ float pl[512];
    __shared__ float red[4][256];
    int g = blockIdx.x;
    int c = threadIdx.x;
    float mx = -INFINITY, sum = 0.0f;
#pragma unroll
    for (int j = 0; j < 16; ++j) {
        size_t base = ((size_t)(g * 16 + j)) * 512;
        mx = fmaxf(mx, partial[base + c]);
        sum += partial[base + 256 + c];
    }
    int len = gb[g + 1] - gb[g];
    pl[c] = (len > 0) ? mx : 0.0f;
    pl[256 + c] = sum / fmaxf((float)len, 1.0f);
    __syncthreads();
    float p[4] = {0, 0, 0, 0};
    for (int k = c; k < 512; k += 256) {
        float pv = pl[k];
#pragma unroll
        for (int cc = 0; cc < 4; ++cc) p[cc] = fmaf(pv, Wd[k * 4 + cc], p[cc]);
    }
#pragma unroll
    for (int cc = 0; cc < 4; ++cc) red[cc][c] = p[cc];
    __syncthreads();
    for (int o = 128; o >= 1; o >>= 1) {
        if (c < o) {
#pragma unroll
            for (int cc = 0; cc < 4; ++cc) red[cc][c] += red[cc][c + o];
        }
        __syncthreads();
    }
    if (c == 0) {
        float l0 = red[0][0] + bd[0], l1 = red[1][0] + bd[1];
        float l2 = red[2][0] + bd[2], l3 = red[3][0] + bd[3];
        float m = fmaxf(fmaxf(l0, l1), fmaxf(l2, l3));
        float ls = m + logf(expf(l0 - m) + expf(l1 - m) + expf(l2 - m) + expf(l3 - m));
        out[g * 4 + 0] = l0 - ls;
        out[g * 4 + 1] = l1 - ls;
        out[g * 4 + 2] = l2 - ls;
        out[g * 4 + 3] = l3 - ls;
    }
}

extern "C" void kernel_launch(void* const* d_in, const int* in_sizes, int n_in,
                              void* d_out, int out_size, void* d_ws, size_t ws_size,
                              hipStream_t stream)
{
    const float* x    = (const float*)d_in[0];
    const float* ew   = (const float*)d_in[1];
    const int*   row  = (const int*)d_in[2];
    const int*   colp = row + NE;
    const int*   batch = (const int*)d_in[3];
    const float* W1 = (const float*)d_in[4];
    const float* b1 = (const float*)d_in[5];
    const float* g1 = (const float*)d_in[6];
    const float* be1 = (const float*)d_in[7];
    const float* W2 = (const float*)d_in[8];
    const float* b2 = (const float*)d_in[9];
    const float* g2 = (const float*)d_in[10];
    const float* be2 = (const float*)d_in[11];
    const float* W3 = (const float*)d_in[12];
    const float* b3 = (const float*)d_in[13];
    const float* g3 = (const float*)d_in[14];
    const float* be3 = (const float*)d_in[15];
    const float* W4 = (const float*)d_in[16];
    const float* b4 = (const float*)d_in[17];
    const float* g4 = (const float*)d_in[18];
    const float* be4 = (const float*)d_in[19];
    const float* W5 = (const float*)d_in[20];
    const float* b5 = (const float*)d_in[21];
    const float* Wd = (const float*)d_in[22];
    const float* bd = (const float*)d_in[23];
    float* outp = (float*)d_out;
    (void)in_sizes; (void)n_in; (void)out_size; (void)ws_size; (void)ew;

    char* wsb = (char*)d_ws;
    size_t off = 0;
    auto take = [&](size_t bytes) -> void* {
        void* p = wsb + off;
        off = (off + bytes + 255) & ~(size_t)255;
        return p;
    };
    int*   cnt    = (int*)take((size_t)NN * sizeof(int));
    float* deg    = (float*)take((size_t)NN * sizeof(float));
    int*   gb     = (int*)take((NG + 1) * sizeof(int));
    unsigned* pslots = (unsigned*)take((size_t)NN * CAP * sizeof(unsigned));
    float* statsA = (float*)take(4 * 256 * sizeof(float));
    float* wcat   = (float*)take(6144 * sizeof(float));
    unsigned short* bt1h = (unsigned short*)take(48 * 128 * 2);
    unsigned short* bt1l = (unsigned short*)take(48 * 128 * 2);
    unsigned short* bt3h = (unsigned short*)take(64 * 96 * 2);
    unsigned short* bt3l = (unsigned short*)take(64 * 96 * 2);
    unsigned short* bt4h = (unsigned short*)take(128 * 192 * 2);
    unsigned short* bt4l = (unsigned short*)take(128 * 192 * 2);
    unsigned short* bt5h = (unsigned short*)take(256 * 384 * 2);
    unsigned short* bt5l = (unsigned short*)take(256 * 384 * 2);
    float* partial= (float*)take((size_t)NG * 16 * 512 * sizeof(float));
    unsigned short* P   = (unsigned short*)take((size_t)NN * 48 * 2);
    unsigned short* uv  = (unsigned short*)take((size_t)NN * 32 * 2);
    unsigned short* Hc2 = (unsigned short*)take((size_t)NN * 48 * 2);
    unsigned short* Hc3 = (unsigned short*)take((size_t)NN * 96 * 2);
    unsigned short* Hc4 = (unsigned short*)take((size_t)NN * 192 * 2);
    unsigned short* Hc5 = (unsigned short*)take((size_t)NN * 384 * 2);
    unsigned short* h5  = (unsigned short*)take((size_t)NN * 256 * 2);

    float* stats1 = statsA;
    float* stats2 = statsA + 256;
    float* stats3 = statsA + 512;
    float* stats4 = statsA + 768;

    hipMemsetAsync(cnt, 0, NN * sizeof(int), stream);
    hipMemsetAsync(deg, 0, NN * sizeof(float), stream);
    hipMemsetAsync(statsA, 0, 4 * 256 * sizeof(float), stream);

    // ---- adjacency build (XCD-partitioned, packed 4B slots, fused deg)
    k_slot2<<<2048, 256, 0, stream>>>(row, colp, ew, cnt, deg, pslots);
    k_dinv<<<196, 256, 0, stream>>>(deg);
    k_repack<<<3125, 256, 0, stream>>>(cnt, pslots, deg);

    // ---- weight prep
    k_wcat1<<<24, 256, 0, stream>>>(W1, wcat);
    k_gbounds<<<1, 128, 0, stream>>>(batch, gb);
    k_wsplit<<<24, 256, 0, stream>>>(wcat, 128, 48, bt1h, bt1l);
    k_wsplit<<<24, 256, 0, stream>>>(W3, 96, 64, bt3h, bt3l);
    k_wsplit<<<96, 256, 0, stream>>>(W4, 192, 128, bt4h, bt4l);
    k_wsplit<<<384, 256, 0, stream>>>(W5, 384, 256, bt5h, bt5l);

    // ---- Layer 1 (128->16): P = x @ [W0-W2 | W1 | W2];  h1 = P0 + prop(P1) + 2*prop(prop(P2)) + b
    k_gemm_mfma_f32A<<<dim3(1, 391), 256, 0, stream>>>(x, 128, bt1h, bt1l, P, 48, NN, 128, 48);
    k_prop<<<1563, 256, 0, stream>>>(cnt, pslots, P, 48, 16, uv, 32, 0, 3, 1.0f,
                                     nullptr, 0, 0, 0.0f, nullptr, 0, 0, nullptr, 0);
    k_prop<<<782, 256, 0, stream>>>(cnt, pslots, uv, 32, 16, Hc2, 48, 0, 2, 2.0f,
                                    P, 48, 0, 1.0f, uv, 32, 0, b1, 1);
    k_bnstats<<<256, 256, 0, stream>>>(Hc2, 48, 4, stats1);
    k_bnapply<<<391, 256, 0, stream>>>(Hc2, 48, 4, stats1, g1, be1);

    // ---- Layer 2 (16->32)
    k_prop<<<782, 256, 0, stream>>>(cnt, pslots, Hc2, 48, 0, Hc2, 48, 16, 2, 1.0f,
                                    nullptr, 0, 0, 0.0f, nullptr, 0, 0, nullptr, 0);
    k_prop<<<782, 256, 0, stream>>>(cnt, pslots, Hc2, 48, 16, Hc2, 48, 32, 2, 2.0f,
                                    Hc2, 48, 0, -1.0f, nullptr, 0, 0, nullptr, 0);
    k_gemm<<<dim3(1, 391), 256, 0, stream>>>(Hc2, 48, W2, 32, Hc3, 96, NN, 48, 32, b2, 1);
    k_bnstats<<<256, 256, 0, stream>>>(Hc3, 96, 5, stats2);
    k_bnapply<<<782, 256, 0, stream>>>(Hc3, 96, 5, stats2, g2, be2);

    // ---- Layer 3 (32->64)
    k_prop<<<1563, 256, 0, stream>>>(cnt, pslots, Hc3, 96, 0, Hc3, 96, 32, 3, 1.0f,
                                     nullptr, 0, 0, 0.0f, nullptr, 0, 0, nullptr, 0);
    k_prop<<<1563, 256, 0, stream>>>(cnt, pslots, Hc3, 96, 32, Hc3, 96, 64, 3, 2.0f,
                                     Hc3, 96, 0, -1.0f, nullptr, 0, 0, nullptr, 0);
    k_gemm_mfma_bf<<<dim3(1, 391), 256, 0, stream>>>(Hc3, 96, bt3h, bt3l, Hc4, 192, NN, 96, 64, b3, 1);
    k_bnstats<<<256, 256, 0, stream>>>(Hc4, 192, 6, stats3);
    k_bnapply<<<1563, 256, 0, stream>>>(Hc4, 192, 6, stats3, g3, be3);

    // ---- Layer 4 (64->128)
    k_prop<<<3125, 256, 0, stream>>>(cnt, pslots, Hc4, 192, 0, Hc4, 192, 64, 4, 1.0f,
                                     nullptr, 0, 0, 0.0f, nullptr, 0, 0, nullptr, 0);
    k_prop<<<3125, 256, 0, stream>>>(cnt, pslots, Hc4, 192, 64, Hc4, 192, 128, 4, 2.0f,
                                     Hc4, 192, 0, -1.0f, nullptr, 0, 0, nullptr, 0);
    k_gemm_mfma_bf<<<dim3(1, 391), 256, 0, stream>>>(Hc4, 192, bt4h, bt4l, Hc5, 384, NN, 192, 128, b4, 1);
    k_bnstats<<<256, 256, 0, stream>>>(Hc5, 384, 7, stats4);
    k_bnapply<<<3125, 256, 0, stream>>>(Hc5, 384, 7, stats4, g4, be4);

    // ---- Layer 5 (128->256), no BN/act, bf16 output
    k_prop<<<6250, 256, 0, stream>>>(cnt, pslots, Hc5, 384, 0, Hc5, 384, 128, 5, 1.0f,
                                     nullptr, 0, 0, 0.0f, nullptr, 0, 0, nullptr, 0);
    k_prop<<<6250, 256, 0, stream>>>(cnt, pslots, Hc5, 384, 128, Hc5, 384, 256, 5, 2.0f,
                                     Hc5, 384, 0, -1.0f, nullptr, 0, 0, nullptr, 0);
    k_gemm_mfma_bf<<<dim3(2, 391), 256, 0, stream>>>(Hc5, 384, bt5h, bt5l, h5, 256, NN, 384, 256, b5, 0);

    // ---- Pool + dense + log_softmax
    k_pool1<<<dim3(16, 64), 256, 0, stream>>>(h5, gb, partial);
    k_pool2d<<<64, 256, 0, stream>>>(partial, gb, Wd, bd, outp);
}

// Round 10
// 800.961 us; speedup vs baseline: 1.1895x; 1.1895x over previous
//
#include <hip/hip_runtime.h>
#include <hip/hip_fp16.h>
#include <cmath>

#define NN 50000
#define NE 1600000
#define NG 64
#define CAP 96    // slots per row; deg ~ Poisson(32), P(deg>=96) ~ e^-41 -> safe
#define NPART 8   // row partitions ~ XCDs; slot region/partition = 2.4 MB < 4 MiB L2
#define PROWS 6250

typedef __attribute__((ext_vector_type(8))) short short8_t;
typedef __attribute__((ext_vector_type(4))) float floatx4;
typedef __attribute__((ext_vector_type(4))) unsigned short us4;
typedef __attribute__((ext_vector_type(8))) unsigned short us8;

static __device__ __forceinline__ float softplusf(float x) {
    return fmaxf(x, 0.0f) + log1pf(expf(-fabsf(x)));
}

static __device__ __forceinline__ float bf2f(unsigned short u) {
    return __uint_as_float(((unsigned)u) << 16);
}
static __device__ __forceinline__ unsigned short f2bf(float x) {
    unsigned u = __float_as_uint(x);
    unsigned t = (u >> 16) & 1u;
    return (unsigned short)((u + 0x7FFFu + t) >> 16);  // RNE
}
static __device__ __forceinline__ float h2f(unsigned u) {
    __half_raw r; r.x = (unsigned short)(u & 0xFFFFu);
    return __half2float(__half(r));
}
static __device__ __forceinline__ unsigned short f2h(float x) {
    __half h = __float2half_rn(x);
    return static_cast<__half_raw>(h).x;
}

// exact split x = hi + lo (bf16 each, ~2^-16 relative residual)
static __device__ __forceinline__ void split_bf16(float x, unsigned short& hi, unsigned short& lo) {
    unsigned u = __float_as_uint(x);
    unsigned hb = u & 0xFFFF0000u;
    hi = (unsigned short)(hb >> 16);
    float r = x - __uint_as_float(hb);   // exact
    lo = f2bf(r);
}

// XCD-partitioned slotted build (r8 version — NO fused deg atomic; a float
// atomicAdd per edge is memory-side and write-throughs its line: r9 showed
// +50 MB WRITE, +74 us). Blocks with (blockIdx&7)==p handle rows
// [p*PROWS,(p+1)*PROWS); slot region (2.4 MB) + cnt stay in that XCD's L2.
__global__ __launch_bounds__(256) void k_slot2(const int* __restrict__ row,
                                               const int* __restrict__ col,
                                               const float* __restrict__ w,
                                               int* __restrict__ cnt,
                                               unsigned* __restrict__ pslots) {
    const int part = blockIdx.x & (NPART - 1);
    const int bid = blockIdx.x >> 3;
    const int nb = gridDim.x >> 3;
    const int rlo = part * PROWS;
    const int rhi = rlo + PROWS;
    for (int e = bid * 256 + threadIdx.x; e < NE; e += nb * 256) {
        int r = row[e];
        if (r >= rlo && r < rhi) {
            int k = atomicAdd(&cnt[r], 1);
            k = min(k, CAP - 1);  // defensive
            pslots[(size_t)r * CAP + k] = ((unsigned)col[e] << 16) | (unsigned)f2h(w[e]);
        }
    }
}

// dinv[r] = rsqrt(sum of raw w over row r), 0 if deg<=0 (atomic-free)
__global__ __launch_bounds__(256) void k_degsum(const int* __restrict__ cnt,
                                                const unsigned* __restrict__ pslots,
                                                float* __restrict__ dinv) {
    int tid = threadIdx.x;
    int lane = tid & 15;
    int node = blockIdx.x * 16 + (tid >> 4);
    if (node >= NN) return;
    int e = cnt[node];
    const unsigned* base = pslots + (size_t)node * CAP;
    float s = 0.0f;
    for (int k = lane; k < e; k += 16) s += h2f(base[k]);
#pragma unroll
    for (int m = 8; m >= 1; m >>= 1) s += __shfl_xor(s, m);
    if (lane == 0) dinv[node] = (s > 0.0f) ? rsqrtf(s) : 0.0f;
}

// In-place: weight half of pslot <- fp16(-w * dinv[r] * dinv[col])
__global__ __launch_bounds__(256) void k_repack(const int* __restrict__ cnt,
                                                unsigned* __restrict__ pslots,
                                                const float* __restrict__ dinv) {
    int tid = threadIdx.x;
    int lane = tid & 15;
    int node = blockIdx.x * 16 + (tid >> 4);
    if (node >= NN) return;
    int e = cnt[node];
    float dr = dinv[node];
    unsigned* pb = pslots + (size_t)node * CAP;
    for (int k = lane; k < e; k += 16) {
        unsigned s = pb[k];
        float wv = -h2f(s) * dr * dinv[s >> 16];
        pb[k] = (s & 0xFFFF0000u) | (unsigned)f2h(wv);
    }
}

// Wcat1 (128 x 48) = [W0-W2 | W1 | W2] from W1 input (3,128,16)
__global__ void k_wcat1(const float* __restrict__ W1, float* __restrict__ wc) {
    int i = blockIdx.x * blockDim.x + threadIdx.x;
    if (i < 128 * 48) {
        int k = i / 48, j = i - k * 48;
        float v;
        if (j < 16)      v = W1[k * 16 + j] - W1[2 * 2048 + k * 16 + j];
        else if (j < 32) v = W1[2048 + k * 16 + (j - 16)];
        else             v = W1[2 * 2048 + k * 16 + (j - 32)];
        wc[i] = v;
    }
}

// Split W (K,N) fp32 into transposed hi/lo bf16: hiT/loT are (N,K)
__global__ void k_wsplit(const float* __restrict__ W, int K, int N,
                         unsigned short* __restrict__ hiT, unsigned short* __restrict__ loT) {
    int idx = blockIdx.x * 256 + threadIdx.x;
    if (idx < K * N) {
        int k = idx / N, n = idx - k * N;
        unsigned short h, l;
        split_bf16(W[idx], h, l);
        hiT[(size_t)n * K + k] = h;
        loT[(size_t)n * K + k] = l;
    }
}

#define ASTR 40  // padded LDS row stride in ushorts (32 + 8)

// ---------------- MFMA GEMM, fp32 A (3-term split), bf16 C. Layer 1 only.
__global__ __launch_bounds__(256, 2) void k_gemm_mfma_f32A(
    const float* __restrict__ A, int lda,
    const unsigned short* __restrict__ BhiT,
    const unsigned short* __restrict__ BloT,
    unsigned short* __restrict__ C, int ldc,
    int M, int K, int Ncol)
{
    __shared__ unsigned short Ah[128 * ASTR];
    __shared__ unsigned short Al[128 * ASTR];
    __shared__ unsigned short Bh[128 * ASTR];
    __shared__ unsigned short Bl[128 * ASTR];

    const int tid = threadIdx.x;
    const int lane = tid & 63;
    const int wave = tid >> 6;
    const int wm = wave >> 1, wn = wave & 1;
    const int quad = lane >> 4, l16 = lane & 15;
    const int bm = blockIdx.y * 128, bn = blockIdx.x * 128;
    const int srow = tid >> 1;
    const int skq  = (tid & 1) * 16;

    floatx4 acc[4][4];
#pragma unroll
    for (int i = 0; i < 4; ++i)
#pragma unroll
        for (int j = 0; j < 4; ++j) acc[i][j] = (floatx4){0.f, 0.f, 0.f, 0.f};

    for (int k0 = 0; k0 < K; k0 += 32) {
        float4 a0 = make_float4(0, 0, 0, 0), a1 = a0, a2 = a0, a3 = a0;
        const int ga = bm + srow;
        if (ga < M) {
            const float* Ap = A + (size_t)ga * lda + k0 + skq;
            a0 = *(const float4*)(Ap + 0);
            a1 = *(const float4*)(Ap + 4);
            a2 = *(const float4*)(Ap + 8);
            a3 = *(const float4*)(Ap + 12);
        }
        uint4 bh0 = make_uint4(0, 0, 0, 0), bh1 = bh0, bl0 = bh0, bl1 = bh0;
        const int gb = bn + srow;
        if (gb < Ncol) {
            const unsigned short* ph = BhiT + (size_t)gb * K + k0 + skq;
            const unsigned short* pl = BloT + (size_t)gb * K + k0 + skq;
            bh0 = *(const uint4*)(ph);
            bh1 = *(const uint4*)(ph + 8);
            bl0 = *(const uint4*)(pl);
            bl1 = *(const uint4*)(pl + 8);
        }
        __attribute__((aligned(16))) unsigned short ah[16], al[16];
        const float av[16] = {a0.x, a0.y, a0.z, a0.w, a1.x, a1.y, a1.z, a1.w,
                              a2.x, a2.y, a2.z, a2.w, a3.x, a3.y, a3.z, a3.w};
#pragma unroll
        for (int i = 0; i < 16; ++i) split_bf16(av[i], ah[i], al[i]);

        __syncthreads();
        *(uint4*)&Ah[srow * ASTR + skq]     = *(const uint4*)&ah[0];
        *(uint4*)&Ah[srow * ASTR + skq + 8] = *(const uint4*)&ah[8];
        *(uint4*)&Al[srow * ASTR + skq]     = *(const uint4*)&al[0];
        *(uint4*)&Al[srow * ASTR + skq + 8] = *(const uint4*)&al[8];
        *(uint4*)&Bh[srow * ASTR + skq]     = bh0;
        *(uint4*)&Bh[srow * ASTR + skq + 8] = bh1;
        *(uint4*)&Bl[srow * ASTR + skq]     = bl0;
        *(uint4*)&Bl[srow * ASTR + skq + 8] = bl1;
        __syncthreads();

        short8_t afh[4], afl[4], bfh[4], bfl[4];
#pragma unroll
        for (int t = 0; t < 4; ++t) {
            const int m = wm * 64 + t * 16 + l16;
            afh[t] = *(const short8_t*)&Ah[m * ASTR + quad * 8];
            afl[t] = *(const short8_t*)&Al[m * ASTR + quad * 8];
            const int n = wn * 64 + t * 16 + l16;
            bfh[t] = *(const short8_t*)&Bh[n * ASTR + quad * 8];
            bfl[t] = *(const short8_t*)&Bl[n * ASTR + quad * 8];
        }
#pragma unroll
        for (int i = 0; i < 4; ++i)
#pragma unroll
            for (int j = 0; j < 4; ++j) {
                acc[i][j] = __builtin_amdgcn_mfma_f32_16x16x32_bf16(afh[i], bfh[j], acc[i][j], 0, 0, 0);
                acc[i][j] = __builtin_amdgcn_mfma_f32_16x16x32_bf16(afh[i], bfl[j], acc[i][j], 0, 0, 0);
                acc[i][j] = __builtin_amdgcn_mfma_f32_16x16x32_bf16(afl[i], bfh[j], acc[i][j], 0, 0, 0);
            }
    }

#pragma unroll
    for (int j = 0; j < 4; ++j) {
        const int col = bn + wn * 64 + j * 16 + l16;
        if (col >= Ncol) continue;
#pragma unroll
        for (int i = 0; i < 4; ++i) {
#pragma unroll
            for (int r = 0; r < 4; ++r) {
                const int row = bm + wm * 64 + i * 16 + quad * 4 + r;
                if (row >= M) continue;
                C[(size_t)row * ldc + col] = f2bf(acc[i][j][r]);
            }
        }
    }
}

// ---------------- MFMA GEMM, bf16 A direct (2-term W split). Layers 3/4/5.
__global__ __launch_bounds__(256, 2) void k_gemm_mfma_bf(
    const unsigned short* __restrict__ A, int lda,
    const unsigned short* __restrict__ BhiT,
    const unsigned short* __restrict__ BloT,
    unsigned short* __restrict__ C, int ldc,
    int M, int K, int Ncol,
    const float* __restrict__ bias, int act)
{
    __shared__ unsigned short Ah[128 * ASTR];
    __shared__ unsigned short Bh[128 * ASTR];
    __shared__ unsigned short Bl[128 * ASTR];

    const int tid = threadIdx.x;
    const int lane = tid & 63;
    const int wave = tid >> 6;
    const int wm = wave >> 1, wn = wave & 1;
    const int quad = lane >> 4, l16 = lane & 15;
    const int bm = blockIdx.y * 128, bn = blockIdx.x * 128;
    const int srow = tid >> 1;
    const int skq  = (tid & 1) * 16;

    floatx4 acc[4][4];
#pragma unroll
    for (int i = 0; i < 4; ++i)
#pragma unroll
        for (int j = 0; j < 4; ++j) acc[i][j] = (floatx4){0.f, 0.f, 0.f, 0.f};

    for (int k0 = 0; k0 < K; k0 += 32) {
        uint4 a0 = make_uint4(0, 0, 0, 0), a1 = a0;
        const int ga = bm + srow;
        if (ga < M) {
            const unsigned short* Ap = A + (size_t)ga * lda + k0 + skq;
            a0 = *(const uint4*)(Ap);
            a1 = *(const uint4*)(Ap + 8);
        }
        uint4 bh0 = make_uint4(0, 0, 0, 0), bh1 = bh0, bl0 = bh0, bl1 = bh0;
        const int gb = bn + srow;
        if (gb < Ncol) {
            const unsigned short* ph = BhiT + (size_t)gb * K + k0 + skq;
            const unsigned short* pl = BloT + (size_t)gb * K + k0 + skq;
            bh0 = *(const uint4*)(ph);
            bh1 = *(const uint4*)(ph + 8);
            bl0 = *(const uint4*)(pl);
            bl1 = *(const uint4*)(pl + 8);
        }
        __syncthreads();
        *(uint4*)&Ah[srow * ASTR + skq]     = a0;
        *(uint4*)&Ah[srow * ASTR + skq + 8] = a1;
        *(uint4*)&Bh[srow * ASTR + skq]     = bh0;
        *(uint4*)&Bh[srow * ASTR + skq + 8] = bh1;
        *(uint4*)&Bl[srow * ASTR + skq]     = bl0;
        *(uint4*)&Bl[srow * ASTR + skq + 8] = bl1;
        __syncthreads();

        short8_t afh[4], bfh[4], bfl[4];
#pragma unroll
        for (int t = 0; t < 4; ++t) {
            const int m = wm * 64 + t * 16 + l16;
            afh[t] = *(const short8_t*)&Ah[m * ASTR + quad * 8];
            const int n = wn * 64 + t * 16 + l16;
            bfh[t] = *(const short8_t*)&Bh[n * ASTR + quad * 8];
            bfl[t] = *(const short8_t*)&Bl[n * ASTR + quad * 8];
        }
#pragma unroll
        for (int i = 0; i < 4; ++i)
#pragma unroll
            for (int j = 0; j < 4; ++j) {
                acc[i][j] = __builtin_amdgcn_mfma_f32_16x16x32_bf16(afh[i], bfh[j], acc[i][j], 0, 0, 0);
                acc[i][j] = __builtin_amdgcn_mfma_f32_16x16x32_bf16(afh[i], bfl[j], acc[i][j], 0, 0, 0);
            }
    }

#pragma unroll
    for (int j = 0; j < 4; ++j) {
        const int col = bn + wn * 64 + j * 16 + l16;
        if (col >= Ncol) continue;
        const float bv = bias ? bias[col] : 0.0f;
#pragma unroll
        for (int i = 0; i < 4; ++i) {
#pragma unroll
            for (int r = 0; r < 4; ++r) {
                const int row = bm + wm * 64 + i * 16 + quad * 4 + r;
                if (row >= M) continue;
                float v = acc[i][j][r] + bv;
                if (act) v = softplusf(v);
                C[(size_t)row * ldc + col] = f2bf(v);
            }
        }
    }
}

// fp32-weight vector GEMM with bf16 A and bf16 C (layer 2 only, K=48)
__global__ __launch_bounds__(256) void k_gemm(
    const unsigned short* __restrict__ A, int lda,
    const float* __restrict__ B, int ldb,
    unsigned short* __restrict__ C, int ldc,
    int M, int K, int Ncol,
    const float* __restrict__ bias, int act)
{
    __shared__ float As[16][128];
    __shared__ float Bs[16][128];
    const int tid = threadIdx.x;
    const int tx = tid & 15;
    const int ty = tid >> 4;
    const int bm = blockIdx.y * 128;
    const int bn = blockIdx.x * 128;
    const int arow = tid >> 1;
    const int akq = (tid & 1) * 8;
    const int bkr = tid >> 4;
    const int bcq = (tid & 15) * 8;

    float acc[8][8];
#pragma unroll
    for (int i = 0; i < 8; ++i)
#pragma unroll
        for (int j = 0; j < 8; ++j) acc[i][j] = 0.0f;

    for (int k0 = 0; k0 < K; k0 += 16) {
        uint4 ald = make_uint4(0, 0, 0, 0);
        int gr = bm + arow;
        if (gr < M) ald = *(const uint4*)(A + (size_t)gr * lda + k0 + akq);
        float4 b0 = make_float4(0, 0, 0, 0), b1 = make_float4(0, 0, 0, 0);
        int cb = bn + bcq;
        const float* Bp = B + (k0 + bkr) * ldb;
        if (cb < Ncol)     b0 = *(const float4*)(Bp + cb);
        if (cb + 4 < Ncol) b1 = *(const float4*)(Bp + cb + 4);
        __syncthreads();
        const unsigned short* au = (const unsigned short*)&ald;
#pragma unroll
        for (int i = 0; i < 8; ++i) As[akq + i][arow] = bf2f(au[i]);
        *(float4*)&Bs[bkr][bcq] = b0;
        *(float4*)&Bs[bkr][bcq + 4] = b1;
        __syncthreads();
#pragma unroll
        for (int kk = 0; kk < 16; ++kk) {
            float a[8], b[8];
            float4 t;
            t = *(const float4*)&As[kk][ty * 4];      a[0] = t.x; a[1] = t.y; a[2] = t.z; a[3] = t.w;
            t = *(const float4*)&As[kk][64 + ty * 4]; a[4] = t.x; a[5] = t.y; a[6] = t.z; a[7] = t.w;
            t = *(const float4*)&Bs[kk][tx * 4];      b[0] = t.x; b[1] = t.y; b[2] = t.z; b[3] = t.w;
            t = *(const float4*)&Bs[kk][64 + tx * 4]; b[4] = t.x; b[5] = t.y; b[6] = t.z; b[7] = t.w;
#pragma unroll
            for (int i = 0; i < 8; ++i)
#pragma unroll
                for (int j = 0; j < 8; ++j)
                    acc[i][j] = fmaf(a[i], b[j], acc[i][j]);
        }
    }
#pragma unroll
    for (int i = 0; i < 8; ++i) {
        int r = bm + ((i < 4) ? (ty * 4 + i) : (64 + ty * 4 + i - 4));
        if (r >= M) continue;
#pragma unroll
        for (int j = 0; j < 8; ++j) {
            int cl = bn + ((j < 4) ? (tx * 4 + j) : (64 + tx * 4 + j - 4));
            if (cl >= Ncol) continue;
            float v = acc[i][j];
            if (bias) v += bias[cl];
            if (act) v = softplusf(v);
            C[(size_t)r * ldc + cl] = f2bf(v);
        }
    }
}

// Slotted propagation (r8 version: packed 4B slots, 4 bf16 feats/lane, x8
// unroll, NORMAL loads — NT slot loads defeated the cross-prop L2 residency
// of the 19.2MB slot array and regressed r9 by ~75 us).
__global__ __launch_bounds__(256) void k_prop(
    const int* __restrict__ cnt, const unsigned* __restrict__ pslots,
    const unsigned short* __restrict__ z, int zld, int zoff,
    unsigned short* __restrict__ out, int outld, int ooff,
    int ltw, float alpha,
    const unsigned short* __restrict__ add1, int a1ld, int a1off, float c1,
    const unsigned short* __restrict__ add2, int a2ld, int a2off,
    const float* __restrict__ bias, int act)
{
    const int T = 1 << ltw;
    const int lane = threadIdx.x & (T - 1);
    const int node = blockIdx.x * (256 >> ltw) + (threadIdx.x >> ltw);
    if (node >= NN) return;
    const int f4 = lane * 4;
    const int e = cnt[node];
    const unsigned* base = pslots + (size_t)node * CAP;
    float accA[4] = {0, 0, 0, 0};
    float accB[4] = {0, 0, 0, 0};
    const unsigned short* zp = z + zoff + f4;
    int p = 0;
    for (; p + 8 <= e; p += 8) {
        unsigned s0 = base[p + 0], s1 = base[p + 1], s2 = base[p + 2], s3 = base[p + 3];
        unsigned s4 = base[p + 4], s5 = base[p + 5], s6 = base[p + 6], s7 = base[p + 7];
        const us4 z0 = *(const us4*)(zp + (size_t)(s0 >> 16) * zld);
        const us4 z1 = *(const us4*)(zp + (size_t)(s1 >> 16) * zld);
        const us4 z2 = *(const us4*)(zp + (size_t)(s2 >> 16) * zld);
        const us4 z3 = *(const us4*)(zp + (size_t)(s3 >> 16) * zld);
        const us4 z4 = *(const us4*)(zp + (size_t)(s4 >> 16) * zld);
        const us4 z5 = *(const us4*)(zp + (size_t)(s5 >> 16) * zld);
        const us4 z6 = *(const us4*)(zp + (size_t)(s6 >> 16) * zld);
        const us4 z7 = *(const us4*)(zp + (size_t)(s7 >> 16) * zld);
        float w0 = h2f(s0), w1 = h2f(s1), w2 = h2f(s2), w3 = h2f(s3);
        float w4 = h2f(s4), w5 = h2f(s5), w6 = h2f(s6), w7 = h2f(s7);
#pragma unroll
        for (int i = 0; i < 4; ++i) {
            accA[i] = fmaf(w0, bf2f(z0[i]), accA[i]);
            accB[i] = fmaf(w1, bf2f(z1[i]), accB[i]);
            accA[i] = fmaf(w2, bf2f(z2[i]), accA[i]);
            accB[i] = fmaf(w3, bf2f(z3[i]), accB[i]);
            accA[i] = fmaf(w4, bf2f(z4[i]), accA[i]);
            accB[i] = fmaf(w5, bf2f(z5[i]), accB[i]);
            accA[i] = fmaf(w6, bf2f(z6[i]), accA[i]);
            accB[i] = fmaf(w7, bf2f(z7[i]), accB[i]);
        }
    }
    for (; p + 4 <= e; p += 4) {
        unsigned s0 = base[p + 0], s1 = base[p + 1], s2 = base[p + 2], s3 = base[p + 3];
        const us4 z0 = *(const us4*)(zp + (size_t)(s0 >> 16) * zld);
        const us4 z1 = *(const us4*)(zp + (size_t)(s1 >> 16) * zld);
        const us4 z2 = *(const us4*)(zp + (size_t)(s2 >> 16) * zld);
        const us4 z3 = *(const us4*)(zp + (size_t)(s3 >> 16) * zld);
        float w0 = h2f(s0), w1 = h2f(s1), w2 = h2f(s2), w3 = h2f(s3);
#pragma unroll
        for (int i = 0; i < 4; ++i) {
            accA[i] = fmaf(w0, bf2f(z0[i]), accA[i]);
            accB[i] = fmaf(w1, bf2f(z1[i]), accB[i]);
            accA[i] = fmaf(w2, bf2f(z2[i]), accA[i]);
            accB[i] = fmaf(w3, bf2f(z3[i]), accB[i]);
        }
    }
    for (; p < e; ++p) {
        unsigned s = base[p];
        float wv = h2f(s);
        const us4 zv = *(const us4*)(zp + (size_t)(s >> 16) * zld);
#pragma unroll
        for (int i = 0; i < 4; ++i) accA[i] = fmaf(wv, bf2f(zv[i]), accA[i]);
    }
#pragma unroll
    for (int i = 0; i < 4; ++i) accA[i] = alpha * (accA[i] + accB[i]);
    if (add1) {
        const us4 t = *(const us4*)(add1 + (size_t)node * a1ld + a1off + f4);
#pragma unroll
        for (int i = 0; i < 4; ++i) accA[i] = fmaf(c1, bf2f(t[i]), accA[i]);
    }
    if (add2) {
        const us4 t = *(const us4*)(add2 + (size_t)node * a2ld + a2off + f4);
#pragma unroll
        for (int i = 0; i < 4; ++i) accA[i] += bf2f(t[i]);
    }
    if (bias) {
        const float4 t = *(const float4*)(bias + f4);
        accA[0] += t.x; accA[1] += t.y; accA[2] += t.z; accA[3] += t.w;
    }
    if (act) {
#pragma unroll
        for (int i = 0; i < 4; ++i) accA[i] = softplusf(accA[i]);
    }
    us4 o;
#pragma unroll
    for (int i = 0; i < 4; ++i) o[i] = f2bf(accA[i]);
    *(us4*)(out + (size_t)node * outld + ooff + f4) = o;
}

__global__ __launch_bounds__(256) void k_bnstats(const unsigned short* __restrict__ h, int ld, int lc,
                                                 float* __restrict__ stats) {
    const int C = 1 << lc;
    const int tid = threadIdx.x;
    const int c = tid & (C - 1);
    const int rpb = 256 >> lc;
    int r = blockIdx.x * rpb + (tid >> lc);
    const int stride = gridDim.x * rpb;
    float s = 0.0f, q = 0.0f;
    for (; r < NN; r += stride) {
        float v = bf2f(h[(size_t)r * ld + c]);
        s += v;
        q = fmaf(v, v, q);
    }
    __shared__ float shs[256], shq[256];
    shs[tid] = s; shq[tid] = q;
    __syncthreads();
    for (int o = 128; o >= C; o >>= 1) {
        if (tid < o) { shs[tid] += shs[tid + o]; shq[tid] += shq[tid + o]; }
        __syncthreads();
    }
    if (tid < C) {
        atomicAdd(&stats[c], shs[tid]);
        atomicAdd(&stats[128 + c], shq[tid]);
    }
}

// Vectorized BN apply: 8 elems/thread.
__global__ void k_bnapply(unsigned short* __restrict__ h, int ld, int lc,
                          const float* __restrict__ stats,
                          const float* __restrict__ g, const float* __restrict__ be) {
    int idx = blockIdx.x * 256 + threadIdx.x;        // in units of 8 elems
    const int C8 = 1 << (lc - 3);
    if (idx >= NN * C8) return;
    int r = idx >> (lc - 3);
    int c0 = (idx & (C8 - 1)) << 3;
    const float invN = 1.0f / (float)NN;
    unsigned short* hp = h + (size_t)r * ld + c0;
    us8 v = *(const us8*)hp;
    us8 o;
#pragma unroll
    for (int i = 0; i < 8; ++i) {
        int c = c0 + i;
        float m = stats[c] * invN;
        float var = fmaf(stats[128 + c], invN, -m * m);
        var = fmaxf(var, 0.0f);
        float inv = rsqrtf(var + 1e-5f);
        o[i] = f2bf(fmaf(g[c] * inv, bf2f(v[i]) - m, be[c]));
    }
    *(us8*)hp = o;
}

static __device__ __forceinline__ int lower_bound_dev(const int* __restrict__ b, int val) {
    int lo = 0, hi = NN;
    while (lo < hi) {
        int mid = (lo + hi) >> 1;
        if (b[mid] < val) lo = mid + 1; else hi = mid;
    }
    return lo;
}

__global__ void k_gbounds(const int* __restrict__ batch, int* __restrict__ gb) {
    int g = threadIdx.x;
    if (g <= NG) gb[g] = (g == NG) ? NN : lower_bound_dev(batch, g);
}

// Pool stage 1 over bf16 h5.
__global__ __launch_bounds__(256) void k_pool1(const unsigned short* __restrict__ h,
                                               const int* __restrict__ gb,
                                               float* __restrict__ partial) {
    int g = blockIdx.y;
    int j = blockIdx.x;
    int start = gb[g], end = gb[g + 1];
    int len = end - start;
    int chunk = (len + 15) >> 4;
    int s = start + j * chunk;
    int e = min(s + chunk, end);
    int c = threadIdx.x;
    float mx = -INFINITY, sum = 0.0f;
    for (int r = s; r < e; ++r) {
        float v = bf2f(h[(size_t)r * 256 + c]);
        mx = fmaxf(mx, v);
        sum += v;
    }
    size_t base = ((size_t)(g * 16 + j)) * 512;
    partial[base + c] = mx;
    partial[base + 256 + c] = sum;
}

// Fused pool stage 2 + dense + log_softmax: 64 blocks.
__global__ __launch_bounds__(256) void k_pool2d(const float* __restrict__ partial,
                                                const int* __restrict__ gb,
                                                const float* __restrict__ Wd,
                                                const float* __restrict__ bd,
                                                float* __restrict__ out) {
    __shared__ float pl[512];
    __shared__ float red[4][256];
    int g = blockIdx.x;
    int c = threadIdx.x;
    float mx = -INFINITY, sum = 0.0f;
#pragma unroll
    for (int j = 0; j < 16; ++j) {
        size_t base = ((size_t)(g * 16 + j)) * 512;
        mx = fmaxf(mx, partial[base + c]);
        sum += partial[base + 256 + c];
    }
    int len = gb[g + 1] - gb[g];
    pl[c] = (len > 0) ? mx : 0.0f;
    pl[256 + c] = sum / fmaxf((float)len, 1.0f);
    __syncthreads();
    float p[4] = {0, 0, 0, 0};
    for (int k = c; k < 512; k += 256) {
        float pv = pl[k];
#pragma unroll
        for (int cc = 0; cc < 4; ++cc) p[cc] = fmaf(pv, Wd[k * 4 + cc], p[cc]);
    }
#pragma unroll
    for (int cc = 0; cc < 4; ++cc) red[cc][c] = p[cc];
    __syncthreads();
    for (int o = 128; o >= 1; o >>= 1) {
        if (c < o) {
#pragma unroll
            for (int cc = 0; cc < 4; ++cc) red[cc][c] += red[cc][c + o];
        }
        __syncthreads();
    }
    if (c == 0) {
        float l0 = red[0][0] + bd[0], l1 = red[1][0] + bd[1];
        float l2 = red[2][0] + bd[2], l3 = red[3][0] + bd[3];
        float m = fmaxf(fmaxf(l0, l1), fmaxf(l2, l3));
        float ls = m + logf(expf(l0 - m) + expf(l1 - m) + expf(l2 - m) + expf(l3 - m));
        out[g * 4 + 0] = l0 - ls;
        out[g * 4 + 1] = l1 - ls;
        out[g * 4 + 2] = l2 - ls;
        out[g * 4 + 3] = l3 - ls;
    }
}

extern "C" void kernel_launch(void* const* d_in, const int* in_sizes, int n_in,
                              void* d_out, int out_size, void* d_ws, size_t ws_size,
                              hipStream_t stream)
{
    const float* x    = (const float*)d_in[0];
    const float* ew   = (const float*)d_in[1];
    const int*   row  = (const int*)d_in[2];
    const int*   colp = row + NE;
    const int*   batch = (const int*)d_in[3];
    const float* W1 = (const float*)d_in[4];
    const float* b1 = (const float*)d_in[5];
    const float* g1 = (const float*)d_in[6];
    const float* be1 = (const float*)d_in[7];
    const float* W2 = (const float*)d_in[8];
    const float* b2 = (const float*)d_in[9];
    const float* g2 = (const float*)d_in[10];
    const float* be2 = (const float*)d_in[11];
    const float* W3 = (const float*)d_in[12];
    const float* b3 = (const float*)d_in[13];
    const float* g3 = (const float*)d_in[14];
    const float* be3 = (const float*)d_in[15];
    const float* W4 = (const float*)d_in[16];
    const float* b4 = (const float*)d_in[17];
    const float* g4 = (const float*)d_in[18];
    const float* be4 = (const float*)d_in[19];
    const float* W5 = (const float*)d_in[20];
    const float* b5 = (const float*)d_in[21];
    const float* Wd = (const float*)d_in[22];
    const float* bd = (const float*)d_in[23];
    float* outp = (float*)d_out;
    (void)in_sizes; (void)n_in; (void)out_size; (void)ws_size; (void)ew;

    char* wsb = (char*)d_ws;
    size_t off = 0;
    auto take = [&](size_t bytes) -> void* {
        void* p = wsb + off;
        off = (off + bytes + 255) & ~(size_t)255;
        return p;
    };
    int*   cnt    = (int*)take((size_t)NN * sizeof(int));
    float* dinv   = (float*)take((size_t)NN * sizeof(float));
    int*   gb     = (int*)take((NG + 1) * sizeof(int));
    unsigned* pslots = (unsigned*)take((size_t)NN * CAP * sizeof(unsigned));
    float* statsA = (float*)take(4 * 256 * sizeof(float));
    float* wcat   = (float*)take(6144 * sizeof(float));
    unsigned short* bt1h = (unsigned short*)take(48 * 128 * 2);
    unsigned short* bt1l = (unsigned short*)take(48 * 128 * 2);
    unsigned short* bt3h = (unsigned short*)take(64 * 96 * 2);
    unsigned short* bt3l = (unsigned short*)take(64 * 96 * 2);
    unsigned short* bt4h = (unsigned short*)take(128 * 192 * 2);
    unsigned short* bt4l = (unsigned short*)take(128 * 192 * 2);
    unsigned short* bt5h = (unsigned short*)take(256 * 384 * 2);
    unsigned short* bt5l = (unsigned short*)take(256 * 384 * 2);
    float* partial= (float*)take((size_t)NG * 16 * 512 * sizeof(float));
    unsigned short* P   = (unsigned short*)take((size_t)NN * 48 * 2);
    unsigned short* uv  = (unsigned short*)take((size_t)NN * 32 * 2);
    unsigned short* Hc2 = (unsigned short*)take((size_t)NN * 48 * 2);
    unsigned short* Hc3 = (unsigned short*)take((size_t)NN * 96 * 2);
    unsigned short* Hc4 = (unsigned short*)take((size_t)NN * 192 * 2);
    unsigned short* Hc5 = (unsigned short*)take((size_t)NN * 384 * 2);
    unsigned short* h5  = (unsigned short*)take((size_t)NN * 256 * 2);

    float* stats1 = statsA;
    float* stats2 = statsA + 256;
    float* stats3 = statsA + 512;
    float* stats4 = statsA + 768;

    hipMemsetAsync(cnt, 0, NN * sizeof(int), stream);
    hipMemsetAsync(statsA, 0, 4 * 256 * sizeof(float), stream);

    // ---- adjacency build (XCD-partitioned, packed 4B slots)
    k_slot2<<<2048, 256, 0, stream>>>(row, colp, ew, cnt, pslots);
    k_degsum<<<3125, 256, 0, stream>>>(cnt, pslots, dinv);
    k_repack<<<3125, 256, 0, stream>>>(cnt, pslots, dinv);

    // ---- weight prep
    k_wcat1<<<24, 256, 0, stream>>>(W1, wcat);
    k_gbounds<<<1, 128, 0, stream>>>(batch, gb);
    k_wsplit<<<24, 256, 0, stream>>>(wcat, 128, 48, bt1h, bt1l);
    k_wsplit<<<24, 256, 0, stream>>>(W3, 96, 64, bt3h, bt3l);
    k_wsplit<<<96, 256, 0, stream>>>(W4, 192, 128, bt4h, bt4l);
    k_wsplit<<<384, 256, 0, stream>>>(W5, 384, 256, bt5h, bt5l);

    // ---- Layer 1 (128->16): P = x @ [W0-W2 | W1 | W2];  h1 = P0 + prop(P1) + 2*prop(prop(P2)) + b
    k_gemm_mfma_f32A<<<dim3(1, 391), 256, 0, stream>>>(x, 128, bt1h, bt1l, P, 48, NN, 128, 48);
    k_prop<<<1563, 256, 0, stream>>>(cnt, pslots, P, 48, 16, uv, 32, 0, 3, 1.0f,
                                     nullptr, 0, 0, 0.0f, nullptr, 0, 0, nullptr, 0);
    k_prop<<<782, 256, 0, stream>>>(cnt, pslots, uv, 32, 16, Hc2, 48, 0, 2, 2.0f,
                                    P, 48, 0, 1.0f, uv, 32, 0, b1, 1);
    k_bnstats<<<256, 256, 0, stream>>>(Hc2, 48, 4, stats1);
    k_bnapply<<<391, 256, 0, stream>>>(Hc2, 48, 4, stats1, g1, be1);

    // ---- Layer 2 (16->32)
    k_prop<<<782, 256, 0, stream>>>(cnt, pslots, Hc2, 48, 0, Hc2, 48, 16, 2, 1.0f,
                                    nullptr, 0, 0, 0.0f, nullptr, 0, 0, nullptr, 0);
    k_prop<<<782, 256, 0, stream>>>(cnt, pslots, Hc2, 48, 16, Hc2, 48, 32, 2, 2.0f,
                                    Hc2, 48, 0, -1.0f, nullptr, 0, 0, nullptr, 0);
    k_gemm<<<dim3(1, 391), 256, 0, stream>>>(Hc2, 48, W2, 32, Hc3, 96, NN, 48, 32, b2, 1);
    k_bnstats<<<256, 256, 0, stream>>>(Hc3, 96, 5, stats2);
    k_bnapply<<<782, 256, 0, stream>>>(Hc3, 96, 5, stats2, g2, be2);

    // ---- Layer 3 (32->64)
    k_prop<<<1563, 256, 0, stream>>>(cnt, pslots, Hc3, 96, 0, Hc3, 96, 32, 3, 1.0f,
                                     nullptr, 0, 0, 0.0f, nullptr, 0, 0, nullptr, 0);
    k_prop<<<1563, 256, 0, stream>>>(cnt, pslots, Hc3, 96, 32, Hc3, 96, 64, 3, 2.0f,
                                     Hc3, 96, 0, -1.0f, nullptr, 0, 0, nullptr, 0);
    k_gemm_mfma_bf<<<dim3(1, 391), 256, 0, stream>>>(Hc3, 96, bt3h, bt3l, Hc4, 192, NN, 96, 64, b3, 1);
    k_bnstats<<<256, 256, 0, stream>>>(Hc4, 192, 6, stats3);
    k_bnapply<<<1563, 256, 0, stream>>>(Hc4, 192, 6, stats3, g3, be3);

    // ---- Layer 4 (64->128)
    k_prop<<<3125, 256, 0, stream>>>(cnt, pslots, Hc4, 192, 0, Hc4, 192, 64, 4, 1.0f,
                                     nullptr, 0, 0, 0.0f, nullptr, 0, 0, nullptr, 0);
    k_prop<<<3125, 256, 0, stream>>>(cnt, pslots, Hc4, 192, 64, Hc4, 192, 128, 4, 2.0f,
                                     Hc4, 192, 0, -1.0f, nullptr, 0, 0, nullptr, 0);
    k_gemm_mfma_bf<<<dim3(1, 391), 256, 0, stream>>>(Hc4, 192, bt4h, bt4l, Hc5, 384, NN, 192, 128, b4, 1);
    k_bnstats<<<256, 256, 0, stream>>>(Hc5, 384, 7, stats4);
    k_bnapply<<<3125, 256, 0, stream>>>(Hc5, 384, 7, stats4, g4, be4);

    // ---- Layer 5 (128->256), no BN/act, bf16 output
    k_prop<<<6250, 256, 0, stream>>>(cnt, pslots, Hc5, 384, 0, Hc5, 384, 128, 5, 1.0f,
                                     nullptr, 0, 0, 0.0f, nullptr, 0, 0, nullptr, 0);
    k_prop<<<6250, 256, 0, stream>>>(cnt, pslots, Hc5, 384, 128, Hc5, 384, 256, 5, 2.0f,
                                     Hc5, 384, 0, -1.0f, nullptr, 0, 0, nullptr, 0);
    k_gemm_mfma_bf<<<dim3(2, 391), 256, 0, stream>>>(Hc5, 384, bt5h, bt5l, h5, 256, NN, 384, 256, b5, 0);

    // ---- Pool + dense + log_softmax
    k_pool1<<<dim3(16, 64), 256, 0, stream>>>(h5, gb, partial);
    k_pool2d<<<64, 256, 0, stream>>>(partial, gb, Wd, bd, outp);
}